// Round 16
// baseline (53.888 us; speedup 1.0000x reference)
//
#include <hip/hip_runtime.h>
#include <hip/hip_bf16.h>
#include <cstdint>

// ExemplarAttention: logits[b,c] = gamma * log( sum_{n: label[n]=c} exp(-beta * d[b,n]) + eps )
// d[b,n] = x2w[b] + e2w[n] - 2 * sum_k (x[b,k]*w[k]) * E[n,k]
//
// Round 16: r15 with its one bug fixed. r15's NaN: the unified CVT1 macro stored RAW x
// to LDS (lost the *w multiply that r10's X path had) -> cross = E.x instead of
// E.(x*w) -> d large-negative -> exp=inf -> inf*0 NaN in one-hot MFMA. Fix: CVT1X
// multiplies by w before cvtpk (r10's validated math). Geometry unchanged from r15:
// 512 thr/(512,2) -> 256 regs/thread; tile 256E x 128B, BK=64 (8 K-iters, 32 MFMA/wave
// per barrier), dbuf 96KB; ch^(row&7) both-sides swizzle; linear 16B/lane writes;
// fused e2w/x2w; one-hot-MFMA class reduce; no atomics.

typedef __attribute__((ext_vector_type(4))) float f32x4;
typedef __attribute__((ext_vector_type(8))) __bf16 bf16x8;
typedef __attribute__((ext_vector_type(4))) _Float16 half4;
typedef __attribute__((ext_vector_type(4))) unsigned int u32x4;

#define DDIM 512
#define NC 10
#define NCP 16
#define NECH 64    // exemplar chunks (16384/256)
#define EPSF 1e-9f

__device__ inline float softplus(float x) {
  return (x > 20.0f) ? x : log1pf(__expf(x));
}

// pack 2 f32 -> 2 bf16 (RNE), lo -> bits[15:0]
__device__ inline unsigned cvtpk(float lo, float hi) {
  unsigned r;
  asm("v_cvt_pk_bf16_f32 %0, %1, %2" : "=v"(r) : "v"(lo), "v"(hi));
  return r;
}

// ---- kernel 1: fused everything-but-final-reduce ----------------------------
// grid: 512 blocks (64 e-tiles x 8 b-tiles), 512 threads = 8 waves (4E x 2B),
// wave tile 64x64. Tile 256E x 128B, BK=64, dbuf LDS 2 x (E 32KB | X 16KB) = 96KB.
// LDS chunk i (16B) within operand block: row = i>>3, pos = i&7; holds global
// kchunk = pos ^ (row&7). Writers store linear (16B/lane); readers use
// byte = row*128 + ((ch ^ (row&7))*16), ks=1 via byte^64.
__global__ __launch_bounds__(512, 2) void gemm_mega(
    const float* __restrict__ x, const float* __restrict__ ex,
    const int* __restrict__ labels, const float* __restrict__ wu,
    const float* __restrict__ bu, float* __restrict__ part) {
  __shared__ __attribute__((aligned(16))) unsigned short smem[2 * 24576];  // 96KB dbuf
  __shared__ float wlds[512];
  __shared__ float sm[16];
  __shared__ float e2l[256];
  __shared__ float x2l[128];
  __shared__ int lab[256];
  const int tid = threadIdx.x, lane = tid & 63, wid = tid >> 6;

  // XCD-aware bijective swizzle: XCD x owns e-tiles [x*8, x*8+8) x 8 b-tiles.
  const int orig = blockIdx.x;             // 0..511
  const int xcd = orig & 7;
  const int local = orig >> 3;             // 0..63
  const int be = xcd * 8 + (local >> 3);   // exemplar tile 0..63
  const int bb = local & 7;                // batch tile 0..7

  if (tid < 256) lab[tid] = labels[be * 256 + tid];

  // ---- in-block softmax(w) + eps -> wlds (all 512 threads) ----
  {
    float v = wu[tid];
    float m = v;
    #pragma unroll
    for (int o = 32; o > 0; o >>= 1) m = fmaxf(m, __shfl_xor(m, o, 64));
    if (lane == 0) sm[wid] = m;
    __syncthreads();
    float mm = sm[0];
    #pragma unroll
    for (int i = 1; i < 8; ++i) mm = fmaxf(mm, sm[i]);
    float e = __expf(v - mm);
    float s = e;
    #pragma unroll
    for (int o = 32; o > 0; o >>= 1) s += __shfl_xor(s, o, 64);
    if (lane == 0) sm[8 + wid] = s;
    __syncthreads();
    float ss = 0.f;
    #pragma unroll
    for (int i = 0; i < 8; ++i) ss += sm[8 + i];
    wlds[tid] = e / ss + EPSF;
    __syncthreads();
  }

  // ---- staging geometry: E 4 chunks/thread (rows r,+64,+128,+192), X 2 chunks ----
  const int srow = tid >> 3;                     // 0..63
  const int kc = (tid & 7) ^ (srow & 7);         // same for all handled rows (+64k)
  const float* eP0 = ex + (size_t)(be * 256 + srow) * DDIM + kc * 8;
  const float* eP1 = eP0 + (size_t)64 * DDIM;
  const float* eP2 = eP0 + (size_t)128 * DDIM;
  const float* eP3 = eP0 + (size_t)192 * DDIM;
  const float* xP0 = x + (size_t)(bb * 128 + srow) * DDIM + kc * 8;
  const float* xP1 = xP0 + (size_t)64 * DDIM;
  const int dE0 = tid * 8, dE1 = (512 + tid) * 8, dE2 = (1024 + tid) * 8, dE3 = (1536 + tid) * 8;
  const int dX0 = 16384 + tid * 8, dX1 = 16384 + (512 + tid) * 8;

  float e20 = 0.f, e21 = 0.f, e22 = 0.f, e23 = 0.f, x20 = 0.f, x21 = 0.f;

  // ---- fragment read byte-offsets (BK=64, ks=0; ks=1 = ^64) ----
  const int WE = (wid >> 1) * 64;    // exemplar base (0,64,128,192)
  const int WB = (wid & 1) * 64;     // batch base (0,64)
  int eoff[4], xoff[4];
  {
    const int ch = lane >> 4;        // 0..3
    #pragma unroll
    for (int f = 0; f < 4; ++f) {
      int er = WE + f * 16 + (lane & 15);
      eoff[f] = er * 128 + ((ch ^ (er & 7)) * 16);
      int xr = WB + f * 16 + (lane & 15);
      xoff[f] = 32768 + xr * 128 + ((ch ^ (xr & 7)) * 16);
    }
  }

  float4 sE0a, sE0b, sE1a, sE1b, sE2a, sE2b, sE3a, sE3b, sX0a, sX0b, sX1a, sX1b;

#define ISSUE(KT) do {                                                  \
    const float* p;                                                     \
    p = eP0 + (KT) * 64; sE0a = *(const float4*)p; sE0b = *(const float4*)(p + 4); \
    p = eP1 + (KT) * 64; sE1a = *(const float4*)p; sE1b = *(const float4*)(p + 4); \
    p = eP2 + (KT) * 64; sE2a = *(const float4*)p; sE2b = *(const float4*)(p + 4); \
    p = eP3 + (KT) * 64; sE3a = *(const float4*)p; sE3b = *(const float4*)(p + 4); \
    p = xP0 + (KT) * 64; sX0a = *(const float4*)p; sX0b = *(const float4*)(p + 4); \
    p = xP1 + (KT) * 64; sX1a = *(const float4*)p; sX1b = *(const float4*)(p + 4); \
  } while (0)

// E: store RAW E as bf16; accumulate e2 += E^2 * w
#define CVT1E(Sa, Sb, ACC, DST, BUFS) do {                              \
    u32x4 pk;                                                           \
    pk[0] = cvtpk(Sa.x, Sa.y); pk[1] = cvtpk(Sa.z, Sa.w);               \
    pk[2] = cvtpk(Sb.x, Sb.y); pk[3] = cvtpk(Sb.z, Sb.w);               \
    ACC += Sa.x*Sa.x*w0.x + Sa.y*Sa.y*w0.y + Sa.z*Sa.z*w0.z + Sa.w*Sa.w*w0.w \
         + Sb.x*Sb.x*w1.x + Sb.y*Sb.y*w1.y + Sb.z*Sb.z*w1.z + Sb.w*Sb.w*w1.w; \
    *(u32x4*)&smem[(BUFS) + (DST)] = pk;                                \
  } while (0)

// X: store x*w as bf16 (THE r15 BUG: this multiply was missing); x2 += (x*w)*x
#define CVT1X(Sa, Sb, ACC, DST, BUFS) do {                              \
    float a0 = Sa.x*w0.x, a1 = Sa.y*w0.y, a2 = Sa.z*w0.z, a3 = Sa.w*w0.w; \
    float a4 = Sb.x*w1.x, a5 = Sb.y*w1.y, a6 = Sb.z*w1.z, a7 = Sb.w*w1.w; \
    u32x4 pk;                                                           \
    pk[0] = cvtpk(a0, a1); pk[1] = cvtpk(a2, a3);                       \
    pk[2] = cvtpk(a4, a5); pk[3] = cvtpk(a6, a7);                       \
    ACC += a0*Sa.x + a1*Sa.y + a2*Sa.z + a3*Sa.w                        \
         + a4*Sb.x + a5*Sb.y + a6*Sb.z + a7*Sb.w;                       \
    *(u32x4*)&smem[(BUFS) + (DST)] = pk;                                \
  } while (0)

#define CVTSTORE(KT, BUFS) do {                                         \
    const float4 w0 = *(const float4*)&wlds[(KT) * 64 + kc * 8];        \
    const float4 w1 = *(const float4*)&wlds[(KT) * 64 + kc * 8 + 4];    \
    CVT1E(sE0a, sE0b, e20, dE0, BUFS);                                  \
    CVT1E(sE1a, sE1b, e21, dE1, BUFS);                                  \
    CVT1E(sE2a, sE2b, e22, dE2, BUFS);                                  \
    CVT1E(sE3a, sE3b, e23, dE3, BUFS);                                  \
    CVT1X(sX0a, sX0b, x20, dX0, BUFS);                                  \
    CVT1X(sX1a, sX1b, x21, dX1, BUFS);                                  \
  } while (0)

#define MFMA_HALF(BASEB, KS) do {                                       \
    const char* base = (const char*)smem + (BASEB);                     \
    bf16x8 ef[4], xf[4];                                                \
    _Pragma("unroll")                                                   \
    for (int f = 0; f < 4; ++f) {                                       \
      ef[f] = *(const bf16x8*)(base + (eoff[f] ^ ((KS) << 6)));         \
      xf[f] = *(const bf16x8*)(base + (xoff[f] ^ ((KS) << 6)));         \
    }                                                                   \
    _Pragma("unroll")                                                   \
    for (int fe = 0; fe < 4; ++fe)                                      \
      _Pragma("unroll")                                                 \
      for (int fb = 0; fb < 4; ++fb)                                    \
        acc[fe][fb] = __builtin_amdgcn_mfma_f32_16x16x32_bf16(          \
            ef[fe], xf[fb], acc[fe][fb], 0, 0, 0);                      \
  } while (0)

  // prologue: stage K-tile 0 into buffer 0
  ISSUE(0);
  CVTSTORE(0, 0);
  __syncthreads();

  f32x4 acc[4][4] = {};
  for (int kt = 0; kt < 8; ++kt) {
    const int cur = kt & 1;
    const int nb = (cur ^ 1) * 24576;              // shorts
    if (kt < 7) ISSUE(kt + 1);                     // loads fly under the MFMA phase
    MFMA_HALF(cur * 49152, 0);
    MFMA_HALF(cur * 49152, 1);
    if (kt < 7) CVTSTORE(kt + 1, nb);
    __syncthreads();   // reads of cur done + next-tile writes visible
  }
#undef ISSUE
#undef CVT1E
#undef CVT1X
#undef CVTSTORE
#undef MFMA_HALF

  // ---- finalize e2w / x2w: sum the 8 pos-threads of each row ----
  #pragma unroll
  for (int o = 1; o < 8; o <<= 1) {
    e20 += __shfl_xor(e20, o, 64); e21 += __shfl_xor(e21, o, 64);
    e22 += __shfl_xor(e22, o, 64); e23 += __shfl_xor(e23, o, 64);
    x20 += __shfl_xor(x20, o, 64); x21 += __shfl_xor(x21, o, 64);
  }
  if ((tid & 7) == 0) {
    e2l[srow] = e20; e2l[64 + srow] = e21;
    e2l[128 + srow] = e22; e2l[192 + srow] = e23;
    x2l[srow] = x20; x2l[64 + srow] = x21;
  }
  __syncthreads();

  // ---- epilogue: sim = exp(-beta*d); class-reduce via one-hot MFMA ----
  const float beta = softplus(bu[0]) + EPSF;
  const int rb = (lane >> 4) * 4;
  const int col = lane & 15;
  float e2v[4][4];
  #pragma unroll
  for (int fe = 0; fe < 4; ++fe)
    #pragma unroll
    for (int r = 0; r < 4; ++r)
      e2v[fe][r] = e2l[WE + fe * 16 + rb + r];
  half4 oh[4];
  #pragma unroll
  for (int fe = 0; fe < 4; ++fe)
    #pragma unroll
    for (int i = 0; i < 4; ++i)
      oh[fe][i] = (lab[WE + fe * 16 + rb + i] == col) ? (_Float16)1.0f : (_Float16)0.0f;

  f32x4 csv[4];
  #pragma unroll
  for (int fb = 0; fb < 4; ++fb) {
    const float xv = x2l[WB + fb * 16 + col];
    f32x4 cs = {0.f, 0.f, 0.f, 0.f};
    #pragma unroll
    for (int fe = 0; fe < 4; ++fe) {
      half4 sa;
      #pragma unroll
      for (int r = 0; r < 4; ++r)
        sa[r] = (_Float16)__expf(-beta * (xv + e2v[fe][r] - 2.0f * acc[fe][fb][r]));
      cs = __builtin_amdgcn_mfma_f32_16x16x16f16(sa, oh[fe], cs, 0, 0, 0);
    }
    csv[fb] = cs;   // cs[r]: class-sum for batch row (WB+fb*16+rb+r), class=col
  }

  // intra-block combine of the 4 exemplar quarters via LDS (reuse smem, 32KB):
  // red[quad][brow_local 128][16], quad = WE>>6.
  float* red = (float*)smem;
  const int quad = WE >> 6;
  #pragma unroll
  for (int fb = 0; fb < 4; ++fb)
    #pragma unroll
    for (int r = 0; r < 4; ++r)
      red[((quad * 128 + (WB + fb * 16 + rb + r)) << 4) | col] = csv[fb][r];
  __syncthreads();

  // sum quarters, store block partial (128 x 16 f32) coalesced (float4/thread)
  {
    const int o = tid * 4;        // 0..2047
    const int rl = o >> 4;        // brow_local 0..127
    const int c0b = o & 12;       // 0,4,8,12
    float4 v0 = *(const float4*)&red[(rl << 4) | c0b];
    float4 v1 = *(const float4*)&red[((128 + rl) << 4) | c0b];
    float4 v2 = *(const float4*)&red[((256 + rl) << 4) | c0b];
    float4 v3 = *(const float4*)&red[((384 + rl) << 4) | c0b];
    float4 r0 = {v0.x + v1.x + v2.x + v3.x, v0.y + v1.y + v2.y + v3.y,
                 v0.z + v1.z + v2.z + v3.z, v0.w + v1.w + v2.w + v3.w};
    *(float4*)&part[(((size_t)(bb * 128 + rl)) * NECH + be) * NCP + c0b] = r0;
  }
}

// ---- kernel 2: logits = gamma * log( sum_ne part[b][ne][c] + eps ) ----------
__global__ __launch_bounds__(256) void reduce_logits(
    const float* __restrict__ part, const float* __restrict__ gu,
    float* __restrict__ out) {
  const int lane = threadIdx.x & 63, wd = threadIdx.x >> 6;
  const int b = blockIdx.x * 4 + wd;
  const int cl = lane & 15, ch0 = lane >> 4;
  const float* p = part + (size_t)b * NECH * NCP;
  float v = 0.f;
  #pragma unroll
  for (int k = 0; k < 16; ++k)
    v += p[(ch0 + 4 * k) * NCP + cl];
  v += __shfl_xor(v, 16, 64);
  v += __shfl_xor(v, 32, 64);
  if (lane < NC) {
    const float gamma = softplus(gu[0]) + EPSF;
    out[b * NC + lane] = gamma * logf(v + EPSF);
  }
}

extern "C" void kernel_launch(void* const* d_in, const int* in_sizes, int n_in,
                              void* d_out, int out_size, void* d_ws, size_t ws_size,
                              hipStream_t stream) {
  const float* x  = (const float*)d_in[0];
  const float* ex = (const float*)d_in[1];
  const int* labels = (const int*)d_in[2];
  const float* wu = (const float*)d_in[3];
  const float* gu = (const float*)d_in[4];
  const float* bu = (const float*)d_in[5];
  float* out = (float*)d_out;
  const int B = in_sizes[0] / DDIM;   // 1024
  const int N = in_sizes[2];          // 16384

  float* part = (float*)d_ws;
  const size_t need = (size_t)B * NECH * NCP * 4;
  if (ws_size < need) return;   // insufficient scratch; fail loudly (zeros)

  gemm_mega<<<(N / 256) * (B / 128), 512, 0, stream>>>(x, ex, labels, wu, bu, part);
  reduce_logits<<<B / 4, 256, 0, stream>>>(part, gu, out);
}

// Round 17
// 38.377 us; speedup vs baseline: 1.4042x; 1.4042x over previous
//
#include <hip/hip_runtime.h>
#include <hip/hip_bf16.h>
#include <cstdint>

// ExemplarAttention: logits[b,c] = gamma * log( sum_{n: label[n]=c} exp(-beta * d[b,n]) + eps )
// d[b,n] = x2w[b] + e2w[n] - 2 * sum_k (x[b,k]*w[k]) * E[n,k]
//
// Round 17: REVERT to round-10 kernel — the verified best (37.8us). Rounds 11-16
// swept the neighborhood (2 blocks/CU DMA staging, depth-2 prefetch, BK=64, coop,
// 8-phase) and every variant regressed or spilled: the (1024,4) 128-reg budget is
// exactly 64 VGPR + 64 AGPR acc (zero slack), so no deeper pipeline fits; fewer
// waves (BK=64@96KB) loses more latency-hiding than longer MFMA phases gain.
// Structure: fully-fused single GEMM pass (in-block softmax(w), reg-staged f32->bf16
// cvt with fused e2w/x2w row sums), 256 blocks x 1024 thr (16 waves, 4Ex4B, 64x64
// wave tiles), BK=32, 64KB dbuf LDS, both-sides (row>>1)&3 swizzle (2-way, free),
// one-hot-MFMA class reduce, coalesced partial stores, no atomics; + reduce kernel.

typedef __attribute__((ext_vector_type(4))) float f32x4;
typedef __attribute__((ext_vector_type(8))) __bf16 bf16x8;
typedef __attribute__((ext_vector_type(4))) _Float16 half4;
typedef __attribute__((ext_vector_type(4))) unsigned int u32x4;

#define DDIM 512
#define NC 10
#define NCP 16
#define NECH 64    // exemplar chunks (16384/256)
#define EPSF 1e-9f

__device__ inline float softplus(float x) {
  return (x > 20.0f) ? x : log1pf(__expf(x));
}

// pack 2 f32 -> 2 bf16 (RNE), lo -> bits[15:0]
__device__ inline unsigned cvtpk(float lo, float hi) {
  unsigned r;
  asm("v_cvt_pk_bf16_f32 %0, %1, %2" : "=v"(r) : "v"(lo), "v"(hi));
  return r;
}

// ---- kernel 1: fused everything-but-final-reduce ----------------------------
// grid: 256 blocks (64 e-tiles x 4 b-tiles), 1024 threads = 16 waves (4E x 4B),
// wave tile 64x64. Tile 256E x 256B, BK=32, dbuf LDS 2 x (E 16KB | X 16KB) = 64KB.
// LDS chunk q (16B): row = q>>2, c = q&3, global kchunk = c ^ ((row>>1)&3).
// Staging thread t = q writes LDS-linear from the pre-swizzled global chunk; fragment
// readers use byte = row*64 + ((ch ^ ((row>>1)&3))*16)   [both-sides swizzle].
__global__ __launch_bounds__(1024, 4) void gemm_mega(
    const float* __restrict__ x, const float* __restrict__ ex,
    const int* __restrict__ labels, const float* __restrict__ wu,
    const float* __restrict__ bu, float* __restrict__ part) {
  __shared__ __attribute__((aligned(16))) unsigned short smem[2 * 16384];  // 64KB dbuf
  __shared__ float wlds[512];
  __shared__ float sm[16];
  __shared__ float e2l[256];
  __shared__ float x2l[256];
  __shared__ int lab[256];
  const int tid = threadIdx.x, lane = tid & 63, wid = tid >> 6;

  // XCD-aware bijective swizzle: XCD x owns e-tiles [x*8, x*8+8) x 4 b-tiles.
  const int orig = blockIdx.x;             // 0..255
  const int xcd = orig & 7;
  const int local = orig >> 3;             // 0..31
  const int be = xcd * 8 + (local >> 2);   // exemplar tile 0..63
  const int bb = local & 3;                // batch tile 0..3

  if (tid < 256) lab[tid] = labels[be * 256 + tid];

  // ---- in-block softmax(w) + eps -> wlds (threads 0..511) ----
  if (tid < 512) {
    float v = wu[tid];
    float m = v;
    #pragma unroll
    for (int o = 32; o > 0; o >>= 1) m = fmaxf(m, __shfl_xor(m, o, 64));
    if (lane == 0) sm[wid] = m;
    __syncthreads();
    float mm = sm[0];
    #pragma unroll
    for (int i = 1; i < 8; ++i) mm = fmaxf(mm, sm[i]);
    float e = __expf(v - mm);
    float s = e;
    #pragma unroll
    for (int o = 32; o > 0; o >>= 1) s += __shfl_xor(s, o, 64);
    if (lane == 0) sm[8 + wid] = s;
    __syncthreads();
    float ss = 0.f;
    #pragma unroll
    for (int i = 0; i < 8; ++i) ss += sm[8 + i];
    wlds[tid] = e / ss + EPSF;
  } else {
    __syncthreads();
    __syncthreads();
  }
  __syncthreads();

  // ---- staging geometry (reg-staged, pre-swizzled source) ----
  const int srow = tid >> 2;                       // 0..255
  const int kc = (tid & 3) ^ ((srow >> 1) & 3);    // fixed k-chunk 0..3 (8 f32 each)
  const float* eP = ex + (size_t)(be * 256 + srow) * DDIM + kc * 8;
  const float* xP = x + (size_t)(bb * 256 + srow) * DDIM + kc * 8;
  const int dE = tid * 8;            // shorts
  const int dX = 8192 + tid * 8;

  float e2a = 0.f, x2a = 0.f;

  // ---- fragment read byte-offsets (BK=32, swizzle-matched) ----
  const int WE = (wid >> 2) * 64;    // exemplar base (0,64,128,192)
  const int WB = (wid & 3) * 64;     // batch base (0,64,128,192)
  int eoff[4], xoff[4];
  {
    const int ch = lane >> 4;        // 0..3
    #pragma unroll
    for (int f = 0; f < 4; ++f) {
      int er = WE + f * 16 + (lane & 15);
      eoff[f] = er * 64 + ((ch ^ ((er >> 1) & 3)) * 16);
      int xr = WB + f * 16 + (lane & 15);
      xoff[f] = 16384 + xr * 64 + ((ch ^ ((xr >> 1) & 3)) * 16);
    }
  }

  float4 sEa, sEb, sXa, sXb;

#define ISSUE(KT) do {                                                  \
    const float* p0 = eP + (KT) * 32;                                   \
    const float* p1 = xP + (KT) * 32;                                   \
    sEa = *(const float4*)p0; sEb = *(const float4*)(p0 + 4);           \
    sXa = *(const float4*)p1; sXb = *(const float4*)(p1 + 4);           \
  } while (0)

#define CVTSTORE(KT, BUFS) do {                                         \
    const float4 w0 = *(const float4*)&wlds[(KT) * 32 + kc * 8];        \
    const float4 w1 = *(const float4*)&wlds[(KT) * 32 + kc * 8 + 4];    \
    u32x4 pk;                                                           \
    pk[0] = cvtpk(sEa.x, sEa.y); pk[1] = cvtpk(sEa.z, sEa.w);           \
    pk[2] = cvtpk(sEb.x, sEb.y); pk[3] = cvtpk(sEb.z, sEb.w);           \
    e2a += sEa.x*sEa.x*w0.x + sEa.y*sEa.y*w0.y                          \
         + sEa.z*sEa.z*w0.z + sEa.w*sEa.w*w0.w                          \
         + sEb.x*sEb.x*w1.x + sEb.y*sEb.y*w1.y                          \
         + sEb.z*sEb.z*w1.z + sEb.w*sEb.w*w1.w;                         \
    *(u32x4*)&smem[(BUFS) + dE] = pk;                                   \
    float a0 = sXa.x*w0.x, a1 = sXa.y*w0.y, a2 = sXa.z*w0.z,            \
          a3 = sXa.w*w0.w, a4 = sXb.x*w1.x, a5 = sXb.y*w1.y,            \
          a6 = sXb.z*w1.z, a7 = sXb.w*w1.w;                             \
    pk[0] = cvtpk(a0, a1); pk[1] = cvtpk(a2, a3);                       \
    pk[2] = cvtpk(a4, a5); pk[3] = cvtpk(a6, a7);                       \
    x2a += a0*sXa.x + a1*sXa.y + a2*sXa.z + a3*sXa.w                    \
         + a4*sXb.x + a5*sXb.y + a6*sXb.z + a7*sXb.w;                   \
    *(u32x4*)&smem[(BUFS) + dX] = pk;                                   \
  } while (0)

  // prologue: stage K-tile 0 into buffer 0
  ISSUE(0);
  CVTSTORE(0, 0);
  __syncthreads();

  f32x4 acc[4][4] = {};
  for (int kt = 0; kt < 16; ++kt) {
    const int cur = kt & 1;
    if (kt < 15) ISSUE(kt + 1);          // loads fly under the MFMA phase
    const char* base = (const char*)smem + cur * 32768;
    bf16x8 ef[4], xf[4];
    #pragma unroll
    for (int f = 0; f < 4; ++f) {
      ef[f] = *(const bf16x8*)(base + eoff[f]);
      xf[f] = *(const bf16x8*)(base + xoff[f]);
    }
    #pragma unroll
    for (int fe = 0; fe < 4; ++fe)
      #pragma unroll
      for (int fb = 0; fb < 4; ++fb)
        acc[fe][fb] = __builtin_amdgcn_mfma_f32_16x16x32_bf16(ef[fe], xf[fb], acc[fe][fb], 0, 0, 0);
    if (kt < 15) CVTSTORE(kt + 1, (cur ^ 1) * 16384);  // write other buffer
    __syncthreads();
  }
#undef ISSUE
#undef CVTSTORE

  // ---- finalize e2w / x2w: sum the 4 kc-threads of each row ----
  e2a += __shfl_xor(e2a, 1, 64); e2a += __shfl_xor(e2a, 2, 64);
  x2a += __shfl_xor(x2a, 1, 64); x2a += __shfl_xor(x2a, 2, 64);
  if ((tid & 3) == 0) {
    e2l[srow] = e2a;
    x2l[srow] = x2a;
  }
  __syncthreads();

  // ---- epilogue: sim = exp(-beta*d); class-reduce via one-hot MFMA ----
  const float beta = softplus(bu[0]) + EPSF;
  const int rb = (lane >> 4) * 4;
  const int col = lane & 15;
  float e2v[4][4];
  #pragma unroll
  for (int fe = 0; fe < 4; ++fe)
    #pragma unroll
    for (int r = 0; r < 4; ++r)
      e2v[fe][r] = e2l[WE + fe * 16 + rb + r];
  half4 oh[4];
  #pragma unroll
  for (int fe = 0; fe < 4; ++fe)
    #pragma unroll
    for (int i = 0; i < 4; ++i)
      oh[fe][i] = (lab[WE + fe * 16 + rb + i] == col) ? (_Float16)1.0f : (_Float16)0.0f;

  f32x4 csv[4];
  #pragma unroll
  for (int fb = 0; fb < 4; ++fb) {
    const float xv = x2l[WB + fb * 16 + col];
    f32x4 cs = {0.f, 0.f, 0.f, 0.f};
    #pragma unroll
    for (int fe = 0; fe < 4; ++fe) {
      half4 sa;
      #pragma unroll
      for (int r = 0; r < 4; ++r)
        sa[r] = (_Float16)__expf(-beta * (xv + e2v[fe][r] - 2.0f * acc[fe][fb][r]));
      cs = __builtin_amdgcn_mfma_f32_16x16x16f16(sa, oh[fe], cs, 0, 0, 0);
    }
    csv[fb] = cs;   // cs[r]: class-sum for batch row (WB+fb*16+rb+r), class=col
  }

  // intra-block combine of the 4 exemplar quarters via LDS (reuse smem, 64KB):
  // red[quad][brow_local 256][16], quad = WE>>6.
  float* red = (float*)smem;
  const int quad = WE >> 6;
  #pragma unroll
  for (int fb = 0; fb < 4; ++fb)
    #pragma unroll
    for (int r = 0; r < 4; ++r)
      red[((quad * 256 + (WB + fb * 16 + rb + r)) << 4) | col] = csv[fb][r];
  __syncthreads();

  // sum quarters, store block partial (256 x 16 f32) coalesced (float4/thread)
  {
    const int o = tid * 4;        // 0..4095
    const int rl = o >> 4;        // brow_local 0..255
    const int c0 = o & 12;        // 0,4,8,12
    float4 v0 = *(const float4*)&red[(rl << 4) | c0];
    float4 v1 = *(const float4*)&red[((256 + rl) << 4) | c0];
    float4 v2 = *(const float4*)&red[((512 + rl) << 4) | c0];
    float4 v3 = *(const float4*)&red[((768 + rl) << 4) | c0];
    float4 r0 = {v0.x + v1.x + v2.x + v3.x, v0.y + v1.y + v2.y + v3.y,
                 v0.z + v1.z + v2.z + v3.z, v0.w + v1.w + v2.w + v3.w};
    *(float4*)&part[(((size_t)(bb * 256 + rl)) * NECH + be) * NCP + c0] = r0;
  }
}

// ---- kernel 2: logits = gamma * log( sum_ne part[b][ne][c] + eps ) ----------
__global__ __launch_bounds__(256) void reduce_logits(
    const float* __restrict__ part, const float* __restrict__ gu,
    float* __restrict__ out) {
  const int lane = threadIdx.x & 63, wd = threadIdx.x >> 6;
  const int b = blockIdx.x * 4 + wd;
  const int cl = lane & 15, ch0 = lane >> 4;
  const float* p = part + (size_t)b * NECH * NCP;
  float v = 0.f;
  #pragma unroll
  for (int k = 0; k < 16; ++k)
    v += p[(ch0 + 4 * k) * NCP + cl];
  v += __shfl_xor(v, 16, 64);
  v += __shfl_xor(v, 32, 64);
  if (lane < NC) {
    const float gamma = softplus(gu[0]) + EPSF;
    out[b * NC + lane] = gamma * logf(v + EPSF);
  }
}

extern "C" void kernel_launch(void* const* d_in, const int* in_sizes, int n_in,
                              void* d_out, int out_size, void* d_ws, size_t ws_size,
                              hipStream_t stream) {
  const float* x  = (const float*)d_in[0];
  const float* ex = (const float*)d_in[1];
  const int* labels = (const int*)d_in[2];
  const float* wu = (const float*)d_in[3];
  const float* gu = (const float*)d_in[4];
  const float* bu = (const float*)d_in[5];
  float* out = (float*)d_out;
  const int B = in_sizes[0] / DDIM;   // 1024
  const int N = in_sizes[2];          // 16384

  float* part = (float*)d_ws;
  const size_t need = (size_t)B * NECH * NCP * 4;
  if (ws_size < need) return;   // insufficient scratch; fail loudly (zeros)

  gemm_mega<<<(N / 256) * (B / 256), 1024, 0, stream>>>(x, ex, labels, wu, bu, part);
  reduce_logits<<<B / 4, 256, 0, stream>>>(part, gu, out);
}

// Round 18
// 38.079 us; speedup vs baseline: 1.4152x; 1.0078x over previous
//
#include <hip/hip_runtime.h>
#include <hip/hip_bf16.h>
#include <cstdint>

// ExemplarAttention: logits[b,c] = gamma * log( sum_{n: label[n]=c} exp(-beta * d[b,n]) + eps )
// d[b,n] = x2w[b] + e2w[n] - 2 * sum_k (x[b,k]*w[k]) * E[n,k]
//
// Round 18: verified-best r10 structure + one safe prologue overlap: ISSUE(0) (first
// K-tile global loads) hoisted ABOVE the in-block softmax, so the first tile's
// ~600-900cyc load latency hides under the softmax's 3 block barriers (once/block,
// 1 block/CU -> directly critical-path). All else identical to r10/r17 (37.8/38.4us):
// fully-fused single GEMM pass (in-block softmax(w), reg-staged f32->bf16 cvt with
// fused e2w/x2w row sums), 256 blocks x 1024 thr (16 waves, 4Ex4B, 64x64 wave tiles),
// BK=32, 64KB dbuf LDS, both-sides (row>>1)&3 swizzle (2-way, free), one-hot-MFMA
// class reduce, coalesced partial stores, no atomics; + reduce kernel.
//
// Structure search closed (r5-r16 postmortems): deeper prefetch spills (128-reg cap
// = 64 VGPR + 64 AGPR exactly), BK=64@96KB loses occupancy (2 waves/SIMD), prep-based
// variants pay the prep back, coop grid.sync costs 160us. Residual gap = LDS-read
// floor (~12.5us, acc-capped 64x64 tiles -> 32.8 FLOP/LDS-byte) + VALU + latency.

typedef __attribute__((ext_vector_type(4))) float f32x4;
typedef __attribute__((ext_vector_type(8))) __bf16 bf16x8;
typedef __attribute__((ext_vector_type(4))) _Float16 half4;
typedef __attribute__((ext_vector_type(4))) unsigned int u32x4;

#define DDIM 512
#define NC 10
#define NCP 16
#define NECH 64    // exemplar chunks (16384/256)
#define EPSF 1e-9f

__device__ inline float softplus(float x) {
  return (x > 20.0f) ? x : log1pf(__expf(x));
}

// pack 2 f32 -> 2 bf16 (RNE), lo -> bits[15:0]
__device__ inline unsigned cvtpk(float lo, float hi) {
  unsigned r;
  asm("v_cvt_pk_bf16_f32 %0, %1, %2" : "=v"(r) : "v"(lo), "v"(hi));
  return r;
}

// ---- kernel 1: fused everything-but-final-reduce ----------------------------
// grid: 256 blocks (64 e-tiles x 4 b-tiles), 1024 threads = 16 waves (4E x 4B),
// wave tile 64x64. Tile 256E x 256B, BK=32, dbuf LDS 2 x (E 16KB | X 16KB) = 64KB.
// LDS chunk q (16B): row = q>>2, c = q&3, global kchunk = c ^ ((row>>1)&3).
// Staging thread t = q writes LDS-linear from the pre-swizzled global chunk; fragment
// readers use byte = row*64 + ((ch ^ ((row>>1)&3))*16)   [both-sides swizzle].
__global__ __launch_bounds__(1024, 4) void gemm_mega(
    const float* __restrict__ x, const float* __restrict__ ex,
    const int* __restrict__ labels, const float* __restrict__ wu,
    const float* __restrict__ bu, float* __restrict__ part) {
  __shared__ __attribute__((aligned(16))) unsigned short smem[2 * 16384];  // 64KB dbuf
  __shared__ float wlds[512];
  __shared__ float sm[16];
  __shared__ float e2l[256];
  __shared__ float x2l[256];
  __shared__ int lab[256];
  const int tid = threadIdx.x, lane = tid & 63, wid = tid >> 6;

  // XCD-aware bijective swizzle: XCD x owns e-tiles [x*8, x*8+8) x 4 b-tiles.
  const int orig = blockIdx.x;             // 0..255
  const int xcd = orig & 7;
  const int local = orig >> 3;             // 0..31
  const int be = xcd * 8 + (local >> 2);   // exemplar tile 0..63
  const int bb = local & 3;                // batch tile 0..3

  if (tid < 256) lab[tid] = labels[be * 256 + tid];

  // ---- staging geometry (reg-staged, pre-swizzled source) ----
  const int srow = tid >> 2;                       // 0..255
  const int kc = (tid & 3) ^ ((srow >> 1) & 3);    // fixed k-chunk 0..3 (8 f32 each)
  const float* eP = ex + (size_t)(be * 256 + srow) * DDIM + kc * 8;
  const float* xP = x + (size_t)(bb * 256 + srow) * DDIM + kc * 8;
  const int dE = tid * 8;            // shorts
  const int dX = 8192 + tid * 8;

  float4 sEa, sEb, sXa, sXb;

#define ISSUE(KT) do {                                                  \
    const float* p0 = eP + (KT) * 32;                                   \
    const float* p1 = xP + (KT) * 32;                                   \
    sEa = *(const float4*)p0; sEb = *(const float4*)(p0 + 4);           \
    sXa = *(const float4*)p1; sXb = *(const float4*)(p1 + 4);           \
  } while (0)

  // issue first K-tile loads NOW: latency hides under the softmax barriers below
  ISSUE(0);

  // ---- in-block softmax(w) + eps -> wlds (threads 0..511) ----
  if (tid < 512) {
    float v = wu[tid];
    float m = v;
    #pragma unroll
    for (int o = 32; o > 0; o >>= 1) m = fmaxf(m, __shfl_xor(m, o, 64));
    if (lane == 0) sm[wid] = m;
    __syncthreads();
    float mm = sm[0];
    #pragma unroll
    for (int i = 1; i < 8; ++i) mm = fmaxf(mm, sm[i]);
    float e = __expf(v - mm);
    float s = e;
    #pragma unroll
    for (int o = 32; o > 0; o >>= 1) s += __shfl_xor(s, o, 64);
    if (lane == 0) sm[8 + wid] = s;
    __syncthreads();
    float ss = 0.f;
    #pragma unroll
    for (int i = 0; i < 8; ++i) ss += sm[8 + i];
    wlds[tid] = e / ss + EPSF;
  } else {
    __syncthreads();
    __syncthreads();
  }
  __syncthreads();

  float e2a = 0.f, x2a = 0.f;

  // ---- fragment read byte-offsets (BK=32, swizzle-matched) ----
  const int WE = (wid >> 2) * 64;    // exemplar base (0,64,128,192)
  const int WB = (wid & 3) * 64;     // batch base (0,64,128,192)
  int eoff[4], xoff[4];
  {
    const int ch = lane >> 4;        // 0..3
    #pragma unroll
    for (int f = 0; f < 4; ++f) {
      int er = WE + f * 16 + (lane & 15);
      eoff[f] = er * 64 + ((ch ^ ((er >> 1) & 3)) * 16);
      int xr = WB + f * 16 + (lane & 15);
      xoff[f] = 16384 + xr * 64 + ((ch ^ ((xr >> 1) & 3)) * 16);
    }
  }

#define CVTSTORE(KT, BUFS) do {                                         \
    const float4 w0 = *(const float4*)&wlds[(KT) * 32 + kc * 8];        \
    const float4 w1 = *(const float4*)&wlds[(KT) * 32 + kc * 8 + 4];    \
    u32x4 pk;                                                           \
    pk[0] = cvtpk(sEa.x, sEa.y); pk[1] = cvtpk(sEa.z, sEa.w);           \
    pk[2] = cvtpk(sEb.x, sEb.y); pk[3] = cvtpk(sEb.z, sEb.w);           \
    e2a += sEa.x*sEa.x*w0.x + sEa.y*sEa.y*w0.y                          \
         + sEa.z*sEa.z*w0.z + sEa.w*sEa.w*w0.w                          \
         + sEb.x*sEb.x*w1.x + sEb.y*sEb.y*w1.y                          \
         + sEb.z*sEb.z*w1.z + sEb.w*sEb.w*w1.w;                         \
    *(u32x4*)&smem[(BUFS) + dE] = pk;                                   \
    float a0 = sXa.x*w0.x, a1 = sXa.y*w0.y, a2 = sXa.z*w0.z,            \
          a3 = sXa.w*w0.w, a4 = sXb.x*w1.x, a5 = sXb.y*w1.y,            \
          a6 = sXb.z*w1.z, a7 = sXb.w*w1.w;                             \
    pk[0] = cvtpk(a0, a1); pk[1] = cvtpk(a2, a3);                       \
    pk[2] = cvtpk(a4, a5); pk[3] = cvtpk(a6, a7);                       \
    x2a += a0*sXa.x + a1*sXa.y + a2*sXa.z + a3*sXa.w                    \
         + a4*sXb.x + a5*sXb.y + a6*sXb.z + a7*sXb.w;                   \
    *(u32x4*)&smem[(BUFS) + dX] = pk;                                   \
  } while (0)

  // prologue: stage K-tile 0 (loads issued pre-softmax) into buffer 0
  CVTSTORE(0, 0);
  __syncthreads();

  f32x4 acc[4][4] = {};
  for (int kt = 0; kt < 16; ++kt) {
    const int cur = kt & 1;
    if (kt < 15) ISSUE(kt + 1);          // loads fly under the MFMA phase
    const char* base = (const char*)smem + cur * 32768;
    bf16x8 ef[4], xf[4];
    #pragma unroll
    for (int f = 0; f < 4; ++f) {
      ef[f] = *(const bf16x8*)(base + eoff[f]);
      xf[f] = *(const bf16x8*)(base + xoff[f]);
    }
    #pragma unroll
    for (int fe = 0; fe < 4; ++fe)
      #pragma unroll
      for (int fb = 0; fb < 4; ++fb)
        acc[fe][fb] = __builtin_amdgcn_mfma_f32_16x16x32_bf16(ef[fe], xf[fb], acc[fe][fb], 0, 0, 0);
    if (kt < 15) CVTSTORE(kt + 1, (cur ^ 1) * 16384);  // write other buffer
    __syncthreads();
  }
#undef ISSUE
#undef CVTSTORE

  // ---- finalize e2w / x2w: sum the 4 kc-threads of each row ----
  e2a += __shfl_xor(e2a, 1, 64); e2a += __shfl_xor(e2a, 2, 64);
  x2a += __shfl_xor(x2a, 1, 64); x2a += __shfl_xor(x2a, 2, 64);
  if ((tid & 3) == 0) {
    e2l[srow] = e2a;
    x2l[srow] = x2a;
  }
  __syncthreads();

  // ---- epilogue: sim = exp(-beta*d); class-reduce via one-hot MFMA ----
  const float beta = softplus(bu[0]) + EPSF;
  const int rb = (lane >> 4) * 4;
  const int col = lane & 15;
  float e2v[4][4];
  #pragma unroll
  for (int fe = 0; fe < 4; ++fe)
    #pragma unroll
    for (int r = 0; r < 4; ++r)
      e2v[fe][r] = e2l[WE + fe * 16 + rb + r];
  half4 oh[4];
  #pragma unroll
  for (int fe = 0; fe < 4; ++fe)
    #pragma unroll
    for (int i = 0; i < 4; ++i)
      oh[fe][i] = (lab[WE + fe * 16 + rb + i] == col) ? (_Float16)1.0f : (_Float16)0.0f;

  f32x4 csv[4];
  #pragma unroll
  for (int fb = 0; fb < 4; ++fb) {
    const float xv = x2l[WB + fb * 16 + col];
    f32x4 cs = {0.f, 0.f, 0.f, 0.f};
    #pragma unroll
    for (int fe = 0; fe < 4; ++fe) {
      half4 sa;
      #pragma unroll
      for (int r = 0; r < 4; ++r)
        sa[r] = (_Float16)__expf(-beta * (xv + e2v[fe][r] - 2.0f * acc[fe][fb][r]));
      cs = __builtin_amdgcn_mfma_f32_16x16x16f16(sa, oh[fe], cs, 0, 0, 0);
    }
    csv[fb] = cs;   // cs[r]: class-sum for batch row (WB+fb*16+rb+r), class=col
  }

  // intra-block combine of the 4 exemplar quarters via LDS (reuse smem, 64KB):
  // red[quad][brow_local 256][16], quad = WE>>6.
  float* red = (float*)smem;
  const int quad = WE >> 6;
  #pragma unroll
  for (int fb = 0; fb < 4; ++fb)
    #pragma unroll
    for (int r = 0; r < 4; ++r)
      red[((quad * 256 + (WB + fb * 16 + rb + r)) << 4) | col] = csv[fb][r];
  __syncthreads();

  // sum quarters, store block partial (256 x 16 f32) coalesced (float4/thread)
  {
    const int o = tid * 4;        // 0..4095
    const int rl = o >> 4;        // brow_local 0..255
    const int c0 = o & 12;        // 0,4,8,12
    float4 v0 = *(const float4*)&red[(rl << 4) | c0];
    float4 v1 = *(const float4*)&red[((256 + rl) << 4) | c0];
    float4 v2 = *(const float4*)&red[((512 + rl) << 4) | c0];
    float4 v3 = *(const float4*)&red[((768 + rl) << 4) | c0];
    float4 r0 = {v0.x + v1.x + v2.x + v3.x, v0.y + v1.y + v2.y + v3.y,
                 v0.z + v1.z + v2.z + v3.z, v0.w + v1.w + v2.w + v3.w};
    *(float4*)&part[(((size_t)(bb * 256 + rl)) * NECH + be) * NCP + c0] = r0;
  }
}

// ---- kernel 2: logits = gamma * log( sum_ne part[b][ne][c] + eps ) ----------
__global__ __launch_bounds__(256) void reduce_logits(
    const float* __restrict__ part, const float* __restrict__ gu,
    float* __restrict__ out) {
  const int lane = threadIdx.x & 63, wd = threadIdx.x >> 6;
  const int b = blockIdx.x * 4 + wd;
  const int cl = lane & 15, ch0 = lane >> 4;
  const float* p = part + (size_t)b * NECH * NCP;
  float v = 0.f;
  #pragma unroll
  for (int k = 0; k < 16; ++k)
    v += p[(ch0 + 4 * k) * NCP + cl];
  v += __shfl_xor(v, 16, 64);
  v += __shfl_xor(v, 32, 64);
  if (lane < NC) {
    const float gamma = softplus(gu[0]) + EPSF;
    out[b * NC + lane] = gamma * logf(v + EPSF);
  }
}

extern "C" void kernel_launch(void* const* d_in, const int* in_sizes, int n_in,
                              void* d_out, int out_size, void* d_ws, size_t ws_size,
                              hipStream_t stream) {
  const float* x  = (const float*)d_in[0];
  const float* ex = (const float*)d_in[1];
  const int* labels = (const int*)d_in[2];
  const float* wu = (const float*)d_in[3];
  const float* gu = (const float*)d_in[4];
  const float* bu = (const float*)d_in[5];
  float* out = (float*)d_out;
  const int B = in_sizes[0] / DDIM;   // 1024
  const int N = in_sizes[2];          // 16384

  float* part = (float*)d_ws;
  const size_t need = (size_t)B * NECH * NCP * 4;
  if (ws_size < need) return;   // insufficient scratch; fail loudly (zeros)

  gemm_mega<<<(N / 256) * (B / 256), 1024, 0, stream>>>(x, ex, labels, wu, bu, part);
  reduce_logits<<<B / 4, 256, 0, stream>>>(part, gu, out);
}